// Round 3
// baseline (474.480 us; speedup 1.0000x reference)
//
#include <hip/hip_runtime.h>

#define Bsz 256
#define Usz 64
#define CVsz 61
#define INsz 3
#define Hsz 1024
#define Gsz 4096
#define NGsz 20
#define NAGsz 10
#define IN2sz 2112

typedef __attribute__((ext_vector_type(8))) short bf16x8;
typedef __attribute__((ext_vector_type(4))) float f32x4;
typedef __attribute__((ext_vector_type(4))) unsigned int u32x4;

__device__ __forceinline__ unsigned int pk2(float x, float y) {
  unsigned int a = __float_as_uint(x), b = __float_as_uint(y);
  return ((a + 0x8000u) >> 16) | ((b + 0x8000u) & 0xffff0000u);
}

__device__ __forceinline__ float sigf(float x) { return 1.f / (1.f + __expf(-x)); }

struct GemmP {
  const float* X1; int ldx1; int nc1; int ldw1;
  const float* Wf1; const float* Wb1;
  const float* Hst; const float* Wf2; const float* Wb2;
  const float* bihf; const float* bhhf; const float* bihb; const float* bhhb;
  float* gout;
  int ksplit; int totc; int ndir; int nW; int ldo;
};

// C[m][n] = sum_k X[m][k] * W[n][k]  (+ optional bias on slice 0)
// block tile 128x128, BK=32, 4 waves 2x2, each wave 64x64 via 4x4 mfma_16x16x32_bf16
__global__ __launch_bounds__(256) void gemm_k(GemmP p) {
  __shared__ __align__(16) unsigned short As[128 * 32];
  __shared__ __align__(16) unsigned short Bs[128 * 32];
  int t = threadIdx.x;
  int n0 = blockIdx.x * 128, m0 = blockIdx.y * 128;
  int z = blockIdx.z;
  int d = (p.ndir == 2) ? (z & 1) : 0;
  int s = (p.ndir == 2) ? (z >> 1) : z;
  const float* Wih = d ? p.Wb1 : p.Wf1;
  const float* Whh = d ? p.Wb2 : p.Wf2;
  const float* Hx = p.Hst + (size_t)d * Bsz * Hsz;
  int c0 = (p.totc * s) / p.ksplit, c1 = (p.totc * (s + 1)) / p.ksplit;
  int wv = t >> 6, ln = t & 63;
  int wr = wv >> 1, wc = wv & 1;
  int fr = ln & 15, kg = ln >> 4;
  int sr = t >> 1, skp = (t & 1) * 16;

  f32x4 acc[4][4];
#pragma unroll
  for (int i = 0; i < 4; i++)
#pragma unroll
    for (int j = 0; j < 4; j++) acc[i][j] = (f32x4){0.f, 0.f, 0.f, 0.f};

  for (int c = c0; c < c1; ++c) {
    const float* Xp; int ldx, kx; const float* Wp; int ldw;
    if (c < p.nc1) { Xp = p.X1; ldx = p.ldx1; kx = c * 32; Wp = Wih; ldw = p.ldw1; }
    else           { Xp = Hx;   ldx = Hsz;    kx = (c - p.nc1) * 32; Wp = Whh; ldw = Hsz; }

    const float* ax = Xp + (size_t)(m0 + sr) * ldx + kx + skp;
    float4 a0 = *(const float4*)(ax);
    float4 a1 = *(const float4*)(ax + 4);
    float4 a2 = *(const float4*)(ax + 8);
    float4 a3 = *(const float4*)(ax + 12);
    int rw = n0 + sr; if (rw >= p.nW) rw = p.nW - 1;
    const float* bx = Wp + (size_t)rw * ldw + kx + skp;
    float4 b0 = *(const float4*)(bx);
    float4 b1 = *(const float4*)(bx + 4);
    float4 b2 = *(const float4*)(bx + 8);
    float4 b3 = *(const float4*)(bx + 12);

    __syncthreads();  // prev iteration's frag reads done before overwrite
    *(u32x4*)(&As[sr * 32 + skp])     = (u32x4){pk2(a0.x, a0.y), pk2(a0.z, a0.w), pk2(a1.x, a1.y), pk2(a1.z, a1.w)};
    *(u32x4*)(&As[sr * 32 + skp + 8]) = (u32x4){pk2(a2.x, a2.y), pk2(a2.z, a2.w), pk2(a3.x, a3.y), pk2(a3.z, a3.w)};
    *(u32x4*)(&Bs[sr * 32 + skp])     = (u32x4){pk2(b0.x, b0.y), pk2(b0.z, b0.w), pk2(b1.x, b1.y), pk2(b1.z, b1.w)};
    *(u32x4*)(&Bs[sr * 32 + skp + 8]) = (u32x4){pk2(b2.x, b2.y), pk2(b2.z, b2.w), pk2(b3.x, b3.y), pk2(b3.z, b3.w)};
    __syncthreads();

    const unsigned short* Ab = &As[(wr * 64 + fr) * 32 + kg * 8];
    const unsigned short* Bb = &Bs[(wc * 64 + fr) * 32 + kg * 8];
    bf16x8 av[4], bv[4];
#pragma unroll
    for (int i = 0; i < 4; i++) av[i] = *(const bf16x8*)(Ab + i * 16 * 32);
#pragma unroll
    for (int j = 0; j < 4; j++) bv[j] = *(const bf16x8*)(Bb + j * 16 * 32);
#pragma unroll
    for (int i = 0; i < 4; i++)
#pragma unroll
      for (int j = 0; j < 4; j++)
        acc[i][j] = __builtin_amdgcn_mfma_f32_16x16x32_bf16(av[i], bv[j], acc[i][j], 0, 0, 0);
  }

  const float* bi = d ? p.bihb : p.bihf;
  const float* bh = d ? p.bhhb : p.bhhf;
  float* outp = p.gout + (size_t)(s * p.ndir + d) * Bsz * p.ldo;
#pragma unroll
  for (int i = 0; i < 4; i++) {
#pragma unroll
    for (int j = 0; j < 4; j++) {
      int col = n0 + wc * 64 + j * 16 + fr;
      float bias = 0.f;
      if (p.bihf && s == 0) bias = bi[col] + bh[col];
#pragma unroll
      for (int r = 0; r < 4; r++) {
        int row = m0 + wr * 64 + i * 16 + kg * 4 + r;
        outp[(size_t)row * p.ldo + col] = acc[i][j][r] + bias;
      }
    }
  }
}

__global__ __launch_bounds__(256) void prep_x1(const float* inp, const float* oldw, float* x1) {
  int idx = blockIdx.x * 256 + threadIdx.x;  // 256*64
  int m = idx >> 6, k = idx & 63;
  x1[idx] = (k < INsz) ? inp[m * INsz + k] : oldw[m * CVsz + (k - INsz)];
}

__global__ __launch_bounds__(256) void cell_k(const float* gates, int ksplit,
    const float* cin, float* hout, float* cout,
    float* dst1, int ld1, int off1, float* dst2, int ld2, int off2) {
  int idx = blockIdx.x * 256 + threadIdx.x;  // [0, 2*B*H)
  int j = idx & (Hsz - 1);
  int m = (idx >> 10) & 255;
  int d = idx >> 18;
  size_t base = ((size_t)d * Bsz + m) * Gsz + j;
  float gi = 0.f, gf = 0.f, gg = 0.f, go = 0.f;
  for (int s = 0; s < ksplit; ++s) {
    const float* gp = gates + (size_t)s * 2 * Bsz * Gsz + base;
    gi += gp[0]; gf += gp[1024]; gg += gp[2048]; go += gp[3072];
  }
  float c = cin[((size_t)d * Bsz + m) * Hsz + j];
  float cn = sigf(gf) * c + sigf(gi) * tanhf(gg);
  float hn = sigf(go) * tanhf(cn);
  hout[((size_t)d * Bsz + m) * Hsz + j] = hn;
  cout[((size_t)d * Bsz + m) * Hsz + j] = cn;
  dst1[(size_t)m * ld1 + off1 + d * Hsz + j] = hn;
  if (dst2) dst2[(size_t)m * ld2 + off2 + d * Hsz + j] = hn;
}

__global__ __launch_bounds__(128) void window_k(const float* x2, const float* Wwin,
    const float* bwin, const float* oldk, const float* inp, const float* cvec,
    const int* tl, float* x2w, float* ophi, float* owin, float* okt) {
  int m = blockIdx.x, t = threadIdx.x, wv = t >> 6, ln = t & 63;
  __shared__ float abk[30];
  __shared__ float phis[Usz];
  const float* o1 = x2 + (size_t)m * IN2sz;  // out1 row (first 2048 cols)
  for (int j = wv; j < 30; j += 2) {
    const float* wr = Wwin + (size_t)j * 2048;
    float sum = 0.f;
    for (int k = ln; k < 2048; k += 64) sum += o1[k] * wr[k];
    for (int off = 32; off; off >>= 1) sum += __shfl_down(sum, off, 64);
    if (ln == 0) abk[j] = __expf(sum + bwin[j]);
  }
  __syncthreads();
  if (t < NAGsz) {
    float kt = oldk[m * NAGsz + t] + abk[20 + t];
    abk[20 + t] = kt;
    okt[m * NAGsz + t] = kt;
  }
  __syncthreads();
  if (t < Usz) {
    float scale = 64.f / (float)tl[0];
    float ph = 0.f;
#pragma unroll
    for (int q = 0; q < NAGsz; ++q) {
      float dk = abk[20 + q] - (float)(t + 1);
      ph += abk[q] * __expf(-abk[10 + q] * dk * dk);
    }
    ph *= scale;
    phis[t] = ph;
    ophi[m * Usz + t] = ph;
  }
  __syncthreads();
  if (t < CVsz) {
    float w = 0.f;
    const float* cv = cvec + (size_t)m * Usz * CVsz + t;
#pragma unroll 4
    for (int u = 0; u < Usz; ++u) w += phis[u] * cv[u * CVsz];
    owin[m * CVsz + t] = w;
    x2w[(size_t)m * IN2sz + 2048 + INsz + t] = w;
  }
  if (t < INsz) x2w[(size_t)m * IN2sz + 2048 + t] = inp[m * INsz + t];
}

__global__ __launch_bounds__(128) void mdn_fin(const float* part, int ks, const float* bm, float* out) {
  int m = blockIdx.x, t = threadIdx.x;
  __shared__ float y[121];
  if (t < 121) {
    float s = bm[t];
    for (int q = 0; q < ks; ++q) s += part[((size_t)q * Bsz + m) * 128 + t];
    y[t] = s;
  }
  __syncthreads();
  if (t == 0) out[m] = sigf(y[0]);
  if (t < NGsz) {
    float mx = -1e30f;
    for (int q = 0; q < NGsz; q++) mx = fmaxf(mx, y[1 + q]);
    float se = 0.f;
    for (int q = 0; q < NGsz; q++) se += __expf(y[1 + q] - mx);
    out[256   + m * NGsz + t] = __expf(y[1 + t] - mx) / se;  // pi
    out[5376  + m * NGsz + t] = y[21 + t];                   // mu1
    out[10496 + m * NGsz + t] = y[41 + t];                   // mu2
    out[15616 + m * NGsz + t] = __expf(y[61 + t]);           // exp(s1)
    out[20736 + m * NGsz + t] = __expf(y[81 + t]);           // exp(s2)
    out[25856 + m * NGsz + t] = tanhf(y[101 + t]);           // tanh(rho)
  }
}

extern "C" void kernel_launch(void* const* d_in, const int* in_sizes, int n_in,
                              void* d_out, int out_size, void* d_ws, size_t ws_size,
                              hipStream_t stream) {
  (void)in_sizes; (void)n_in; (void)out_size;
  const float* inp  = (const float*)d_in[0];
  const float* cvec = (const float*)d_in[1];
  const float* oldk = (const float*)d_in[2];
  const float* oldw = (const float*)d_in[3];
  const float* h1   = (const float*)d_in[4];
  const float* c1   = (const float*)d_in[5];
  const float* h2   = (const float*)d_in[6];
  const float* c2   = (const float*)d_in[7];
  const int*   tl   = (const int*)d_in[8];
  float* out = (float*)d_out;
  float* ws  = (float*)d_ws;

  float* ws_x1  = ws;                   // 16384
  float* ws_x2  = ws + 16384;           // 540672 (256 x 2112)
  float* ws_cat = ws_x2 + 540672;       // 1048576 (256 x 4096)
  float* ws_mdn = ws_cat + 1048576;     // 262144 (8 x 256 x 128)
  float* ws_g   = ws_mdn + 262144;      // ksplit * 2 * 1048576

  size_t fixed = (size_t)16384 + 540672 + 1048576 + 262144;
  int ksplit = 4;
  while (ksplit > 1 && (fixed + (size_t)ksplit * 2 * 1048576) * 4 > ws_size) ksplit >>= 1;

  prep_x1<<<64, 256, 0, stream>>>(inp, oldw, ws_x1);

  GemmP g1{};
  g1.X1 = ws_x1; g1.ldx1 = 64; g1.nc1 = 2; g1.ldw1 = 64;
  g1.Wf1 = (const float*)d_in[9];  g1.Wb1 = (const float*)d_in[13];
  g1.Hst = h1; g1.Wf2 = (const float*)d_in[10]; g1.Wb2 = (const float*)d_in[14];
  g1.bihf = (const float*)d_in[11]; g1.bhhf = (const float*)d_in[12];
  g1.bihb = (const float*)d_in[15]; g1.bhhb = (const float*)d_in[16];
  g1.gout = ws_g; g1.ksplit = ksplit; g1.totc = 34; g1.ndir = 2; g1.nW = 4096; g1.ldo = 4096;
  gemm_k<<<dim3(32, 2, 2 * ksplit), 256, 0, stream>>>(g1);

  cell_k<<<2048, 256, 0, stream>>>(ws_g, ksplit, c1, out + 65536, out + 589824,
                                   ws_x2, IN2sz, 0, ws_cat, 4096, 0);

  window_k<<<256, 128, 0, stream>>>(ws_x2, (const float*)d_in[25], (const float*)d_in[26],
                                    oldk, inp, cvec, tl, ws_x2,
                                    out + 30976, out + 47360, out + 62976);

  GemmP g2{};
  g2.X1 = ws_x2; g2.ldx1 = IN2sz; g2.nc1 = 66; g2.ldw1 = IN2sz;
  g2.Wf1 = (const float*)d_in[17]; g2.Wb1 = (const float*)d_in[21];
  g2.Hst = h2; g2.Wf2 = (const float*)d_in[18]; g2.Wb2 = (const float*)d_in[22];
  g2.bihf = (const float*)d_in[19]; g2.bhhf = (const float*)d_in[20];
  g2.bihb = (const float*)d_in[23]; g2.bhhb = (const float*)d_in[24];
  g2.gout = ws_g; g2.ksplit = ksplit; g2.totc = 98; g2.ndir = 2; g2.nW = 4096; g2.ldo = 4096;
  gemm_k<<<dim3(32, 2, 2 * ksplit), 256, 0, stream>>>(g2);

  cell_k<<<2048, 256, 0, stream>>>(ws_g, ksplit, c2, out + 1114112, out + 1638400,
                                   ws_cat, 4096, 2048, nullptr, 0, 0);

  GemmP gm{};
  gm.X1 = ws_cat; gm.ldx1 = 4096; gm.nc1 = 128; gm.ldw1 = 4096;
  gm.Wf1 = (const float*)d_in[27]; gm.Wb1 = (const float*)d_in[27];
  gm.Hst = ws_cat; gm.Wf2 = ws_cat; gm.Wb2 = ws_cat;
  gm.bihf = nullptr; gm.bhhf = nullptr; gm.bihb = nullptr; gm.bhhb = nullptr;
  gm.gout = ws_mdn; gm.ksplit = 8; gm.totc = 128; gm.ndir = 1; gm.nW = 121; gm.ldo = 128;
  gemm_k<<<dim3(1, 2, 8), 256, 0, stream>>>(gm);

  mdn_fin<<<256, 128, 0, stream>>>(ws_mdn, 8, (const float*)d_in[28], out);
}

// Round 6
// 314.595 us; speedup vs baseline: 1.5082x; 1.5082x over previous
//
#include <hip/hip_runtime.h>

#define Bsz 256
#define Usz 64
#define CVsz 61
#define INsz 3
#define Hsz 1024
#define Gsz 4096
#define NGsz 20
#define NAGsz 10
#define IN2sz 2112

typedef __attribute__((ext_vector_type(8))) short bf16x8;
typedef __attribute__((ext_vector_type(4))) float f32x4;
typedef __attribute__((ext_vector_type(4))) unsigned int u32x4;

__device__ __forceinline__ unsigned int pk2(float x, float y) {
  unsigned int a = __float_as_uint(x), b = __float_as_uint(y);
  return ((a + 0x8000u) >> 16) | ((b + 0x8000u) & 0xffff0000u);
}

__device__ __forceinline__ float sigf(float x) { return 1.f / (1.f + __expf(-x)); }

struct GemmP {
  const float* X1; int ldx1; int nc1; int ldw1;
  const float* Wf1; const float* Wb1;
  const float* Hst; const float* Wf2; const float* Wb2;
  const float* bihf; const float* bhhf; const float* bihb; const float* bhhb;
  float* gout;
  int ksplit; int totc; int ndir; int nW; int ldo;
};

// C[m][n] = sum_k X[m][k] * W[n][k]  (+ optional bias on slice 0)
// block tile 128x128, BK=32, 4 waves 2x2, each wave 64x64 via 4x4 mfma_16x16x32_bf16
__global__ __launch_bounds__(256) void gemm_k(GemmP p) {
  __shared__ __align__(16) unsigned short As[128 * 32];
  __shared__ __align__(16) unsigned short Bs[128 * 32];
  int t = threadIdx.x;
  int n0 = blockIdx.x * 128, m0 = blockIdx.y * 128;
  int z = blockIdx.z;
  int d = (p.ndir == 2) ? (z & 1) : 0;
  int s = (p.ndir == 2) ? (z >> 1) : z;
  const float* Wih = d ? p.Wb1 : p.Wf1;
  const float* Whh = d ? p.Wb2 : p.Wf2;
  const float* Hx = p.Hst + (size_t)d * Bsz * Hsz;
  int c0 = (p.totc * s) / p.ksplit, c1 = (p.totc * (s + 1)) / p.ksplit;
  int wv = t >> 6, ln = t & 63;
  int wr = wv >> 1, wc = wv & 1;
  int fr = ln & 15, kg = ln >> 4;
  int sr = t >> 1, skp = (t & 1) * 16;

  f32x4 acc[4][4];
#pragma unroll
  for (int i = 0; i < 4; i++)
#pragma unroll
    for (int j = 0; j < 4; j++) acc[i][j] = (f32x4){0.f, 0.f, 0.f, 0.f};

  for (int c = c0; c < c1; ++c) {
    const float* Xp; int ldx, kx; const float* Wp; int ldw;
    if (c < p.nc1) { Xp = p.X1; ldx = p.ldx1; kx = c * 32; Wp = Wih; ldw = p.ldw1; }
    else           { Xp = Hx;   ldx = Hsz;    kx = (c - p.nc1) * 32; Wp = Whh; ldw = Hsz; }

    const float* ax = Xp + (size_t)(m0 + sr) * ldx + kx + skp;
    float4 a0 = *(const float4*)(ax);
    float4 a1 = *(const float4*)(ax + 4);
    float4 a2 = *(const float4*)(ax + 8);
    float4 a3 = *(const float4*)(ax + 12);
    int rw = n0 + sr; if (rw >= p.nW) rw = p.nW - 1;
    const float* bx = Wp + (size_t)rw * ldw + kx + skp;
    float4 b0 = *(const float4*)(bx);
    float4 b1 = *(const float4*)(bx + 4);
    float4 b2 = *(const float4*)(bx + 8);
    float4 b3 = *(const float4*)(bx + 12);

    __syncthreads();  // prev iteration's frag reads done before overwrite
    *(u32x4*)(&As[sr * 32 + skp])     = (u32x4){pk2(a0.x, a0.y), pk2(a0.z, a0.w), pk2(a1.x, a1.y), pk2(a1.z, a1.w)};
    *(u32x4*)(&As[sr * 32 + skp + 8]) = (u32x4){pk2(a2.x, a2.y), pk2(a2.z, a2.w), pk2(a3.x, a3.y), pk2(a3.z, a3.w)};
    *(u32x4*)(&Bs[sr * 32 + skp])     = (u32x4){pk2(b0.x, b0.y), pk2(b0.z, b0.w), pk2(b1.x, b1.y), pk2(b1.z, b1.w)};
    *(u32x4*)(&Bs[sr * 32 + skp + 8]) = (u32x4){pk2(b2.x, b2.y), pk2(b2.z, b2.w), pk2(b3.x, b3.y), pk2(b3.z, b3.w)};
    __syncthreads();

    const unsigned short* Ab = &As[(wr * 64 + fr) * 32 + kg * 8];
    const unsigned short* Bb = &Bs[(wc * 64 + fr) * 32 + kg * 8];
    bf16x8 av[4], bv[4];
#pragma unroll
    for (int i = 0; i < 4; i++) av[i] = *(const bf16x8*)(Ab + i * 16 * 32);
#pragma unroll
    for (int j = 0; j < 4; j++) bv[j] = *(const bf16x8*)(Bb + j * 16 * 32);
#pragma unroll
    for (int i = 0; i < 4; i++)
#pragma unroll
      for (int j = 0; j < 4; j++)
        acc[i][j] = __builtin_amdgcn_mfma_f32_16x16x32_bf16(av[i], bv[j], acc[i][j], 0, 0, 0);
  }

  const float* bi = d ? p.bihb : p.bihf;
  const float* bh = d ? p.bhhb : p.bhhf;
  float* outp = p.gout + (size_t)(s * p.ndir + d) * Bsz * p.ldo;
#pragma unroll
  for (int i = 0; i < 4; i++) {
#pragma unroll
    for (int j = 0; j < 4; j++) {
      int col = n0 + wc * 64 + j * 16 + fr;
      float bias = 0.f;
      if (p.bihf && s == 0) bias = bi[col] + bh[col];
#pragma unroll
      for (int r = 0; r < 4; r++) {
        int row = m0 + wr * 64 + i * 16 + kg * 4 + r;
        outp[(size_t)row * p.ldo + col] = acc[i][j][r] + bias;
      }
    }
  }
}

__global__ __launch_bounds__(256) void prep_x1(const float* inp, const float* oldw, float* x1) {
  int idx = blockIdx.x * 256 + threadIdx.x;  // 256*64
  int m = idx >> 6, k = idx & 63;
  x1[idx] = (k < INsz) ? inp[m * INsz + k] : oldw[m * CVsz + (k - INsz)];
}

__global__ __launch_bounds__(256) void cell_k(const float* gates, int ksplit,
    const float* cin, float* hout, float* cout,
    float* dst1, int ld1, int off1, float* dst2, int ld2, int off2) {
  int idx = blockIdx.x * 256 + threadIdx.x;  // [0, 2*B*H)
  int j = idx & (Hsz - 1);
  int m = (idx >> 10) & 255;
  int d = idx >> 18;
  size_t base = ((size_t)d * Bsz + m) * Gsz + j;
  float gi = 0.f, gf = 0.f, gg = 0.f, go = 0.f;
  for (int s = 0; s < ksplit; ++s) {
    const float* gp = gates + (size_t)s * 2 * Bsz * Gsz + base;
    gi += gp[0]; gf += gp[1024]; gg += gp[2048]; go += gp[3072];
  }
  float c = cin[((size_t)d * Bsz + m) * Hsz + j];
  float cn = sigf(gf) * c + sigf(gi) * tanhf(gg);
  float hn = sigf(go) * tanhf(cn);
  hout[((size_t)d * Bsz + m) * Hsz + j] = hn;
  cout[((size_t)d * Bsz + m) * Hsz + j] = cn;
  dst1[(size_t)m * ld1 + off1 + d * Hsz + j] = hn;
  if (dst2) dst2[(size_t)m * ld2 + off2 + d * Hsz + j] = hn;
}

// Reduce win-projection partials, compute abk/k_t/phi/win, scatter into x2.
__global__ __launch_bounds__(128) void win_fin(const float* winp, int ks,
    const float* bwin, const float* oldk, const float* inp, const float* cvec,
    const int* tl, float* x2w, float* ophi, float* owin, float* okt) {
  int m = blockIdx.x, t = threadIdx.x, wv = t >> 6, ln = t & 63;
  __shared__ float abk[30];
  __shared__ float phis[Usz];
  __shared__ float wpart[2][CVsz];
  if (t < 30) {
    float s = bwin[t];
    for (int q = 0; q < ks; ++q) s += winp[((size_t)q * Bsz + m) * 128 + t];
    abk[t] = __expf(s);
  }
  __syncthreads();
  if (t < NAGsz) {
    float kt = oldk[m * NAGsz + t] + abk[20 + t];
    abk[20 + t] = kt;
    okt[m * NAGsz + t] = kt;
  }
  __syncthreads();
  if (t < Usz) {
    float scale = 64.f / (float)tl[0];
    float ph = 0.f;
#pragma unroll
    for (int q = 0; q < NAGsz; ++q) {
      float dk = abk[20 + q] - (float)(t + 1);
      ph += abk[q] * __expf(-abk[10 + q] * dk * dk);
    }
    ph *= scale;
    phis[t] = ph;
    ophi[m * Usz + t] = ph;
  }
  __syncthreads();
  if (ln < CVsz) {  // win: u-range split across the 2 waves, independent loads
    float w = 0.f;
    const float* cv = cvec + (size_t)m * Usz * CVsz + (size_t)wv * 32 * CVsz + ln;
#pragma unroll
    for (int u = 0; u < 32; ++u) w += phis[wv * 32 + u] * cv[u * CVsz];
    wpart[wv][ln] = w;
  }
  __syncthreads();
  if (t < CVsz) {
    float w = wpart[0][t] + wpart[1][t];
    owin[m * CVsz + t] = w;
    x2w[(size_t)m * IN2sz + 2048 + INsz + t] = w;
  }
  if (t < INsz) x2w[(size_t)m * IN2sz + 2048 + t] = inp[m * INsz + t];
}

__global__ __launch_bounds__(128) void mdn_fin(const float* part, int ks, const float* bm, float* out) {
  int m = blockIdx.x, t = threadIdx.x;
  __shared__ float y[121];
  if (t < 121) {
    float s = bm[t];
    for (int q = 0; q < ks; ++q) s += part[((size_t)q * Bsz + m) * 128 + t];
    y[t] = s;
  }
  __syncthreads();
  if (t == 0) out[m] = sigf(y[0]);
  if (t < NGsz) {
    float mx = -1e30f;
    for (int q = 0; q < NGsz; q++) mx = fmaxf(mx, y[1 + q]);
    float se = 0.f;
    for (int q = 0; q < NGsz; q++) se += __expf(y[1 + q] - mx);
    out[256   + m * NGsz + t] = __expf(y[1 + t] - mx) / se;  // pi
    out[5376  + m * NGsz + t] = y[21 + t];                   // mu1
    out[10496 + m * NGsz + t] = y[41 + t];                   // mu2
    out[15616 + m * NGsz + t] = __expf(y[61 + t]);           // exp(s1)
    out[20736 + m * NGsz + t] = __expf(y[81 + t]);           // exp(s2)
    out[25856 + m * NGsz + t] = tanhf(y[101 + t]);           // tanh(rho)
  }
}

extern "C" void kernel_launch(void* const* d_in, const int* in_sizes, int n_in,
                              void* d_out, int out_size, void* d_ws, size_t ws_size,
                              hipStream_t stream) {
  (void)in_sizes; (void)n_in; (void)out_size;
  const float* inp  = (const float*)d_in[0];
  const float* cvec = (const float*)d_in[1];
  const float* oldk = (const float*)d_in[2];
  const float* oldw = (const float*)d_in[3];
  const float* h1   = (const float*)d_in[4];
  const float* c1   = (const float*)d_in[5];
  const float* h2   = (const float*)d_in[6];
  const float* c2   = (const float*)d_in[7];
  const int*   tl   = (const int*)d_in[8];
  float* out = (float*)d_out;
  float* ws  = (float*)d_ws;

  float* ws_x1   = ws;                    // 16384
  float* ws_x2   = ws + 16384;            // 540672 (256 x 2112)
  float* ws_cat  = ws_x2 + 540672;        // 1048576 (256 x 4096)
  float* ws_mdn  = ws_cat + 1048576;      // 262144 (8 x 256 x 128)
  float* ws_winp = ws_mdn + 262144;       // 262144 (8 x 256 x 128)
  float* ws_g    = ws_winp + 262144;      // ksplit * 2 * 1048576

  size_t fixed = (size_t)16384 + 540672 + 1048576 + 262144 + 262144;
  int ksplit = 4;
  while (ksplit > 1 && (fixed + (size_t)ksplit * 2 * 1048576) * 4 > ws_size) ksplit >>= 1;

  prep_x1<<<64, 256, 0, stream>>>(inp, oldw, ws_x1);

  GemmP g1{};
  g1.X1 = ws_x1; g1.ldx1 = 64; g1.nc1 = 2; g1.ldw1 = 64;
  g1.Wf1 = (const float*)d_in[9];  g1.Wb1 = (const float*)d_in[13];
  g1.Hst = h1; g1.Wf2 = (const float*)d_in[10]; g1.Wb2 = (const float*)d_in[14];
  g1.bihf = (const float*)d_in[11]; g1.bhhf = (const float*)d_in[12];
  g1.bihb = (const float*)d_in[15]; g1.bhhb = (const float*)d_in[16];
  g1.gout = ws_g; g1.ksplit = ksplit; g1.totc = 34; g1.ndir = 2; g1.nW = 4096; g1.ldo = 4096;
  gemm_k<<<dim3(32, 2, 2 * ksplit), 256, 0, stream>>>(g1);

  cell_k<<<2048, 256, 0, stream>>>(ws_g, ksplit, c1, out + 65536, out + 589824,
                                   ws_x2, IN2sz, 0, ws_cat, 4096, 0);

  // win projection: [256,2048] x [30,2048]^T via MFMA gemm, K-split x8
  GemmP gw{};
  gw.X1 = ws_x2; gw.ldx1 = IN2sz; gw.nc1 = 64; gw.ldw1 = 2048;
  gw.Wf1 = (const float*)d_in[25]; gw.Wb1 = (const float*)d_in[25];
  gw.Hst = ws_x2; gw.Wf2 = (const float*)d_in[25]; gw.Wb2 = (const float*)d_in[25];
  gw.bihf = nullptr; gw.bhhf = nullptr; gw.bihb = nullptr; gw.bhhb = nullptr;
  gw.gout = ws_winp; gw.ksplit = 8; gw.totc = 64; gw.ndir = 1; gw.nW = 30; gw.ldo = 128;
  gemm_k<<<dim3(1, 2, 8), 256, 0, stream>>>(gw);

  win_fin<<<256, 128, 0, stream>>>(ws_winp, 8, (const float*)d_in[26],
                                   oldk, inp, cvec, tl, ws_x2,
                                   out + 30976, out + 47360, out + 62976);

  GemmP g2{};
  g2.X1 = ws_x2; g2.ldx1 = IN2sz; g2.nc1 = 66; g2.ldw1 = IN2sz;
  g2.Wf1 = (const float*)d_in[17]; g2.Wb1 = (const float*)d_in[21];
  g2.Hst = h2; g2.Wf2 = (const float*)d_in[18]; g2.Wb2 = (const float*)d_in[22];
  g2.bihf = (const float*)d_in[19]; g2.bhhf = (const float*)d_in[20];
  g2.bihb = (const float*)d_in[23]; g2.bhhb = (const float*)d_in[24];
  g2.gout = ws_g; g2.ksplit = ksplit; g2.totc = 98; g2.ndir = 2; g2.nW = 4096; g2.ldo = 4096;
  gemm_k<<<dim3(32, 2, 2 * ksplit), 256, 0, stream>>>(g2);

  cell_k<<<2048, 256, 0, stream>>>(ws_g, ksplit, c2, out + 1114112, out + 1638400,
                                   ws_cat, 4096, 2048, nullptr, 0, 0);

  GemmP gm{};
  gm.X1 = ws_cat; gm.ldx1 = 4096; gm.nc1 = 128; gm.ldw1 = 4096;
  gm.Wf1 = (const float*)d_in[27]; gm.Wb1 = (const float*)d_in[27];
  gm.Hst = ws_cat; gm.Wf2 = ws_cat; gm.Wb2 = ws_cat;
  gm.bihf = nullptr; gm.bhhf = nullptr; gm.bihb = nullptr; gm.bhhb = nullptr;
  gm.gout = ws_mdn; gm.ksplit = 8; gm.totc = 128; gm.ndir = 1; gm.nW = 121; gm.ldo = 128;
  gemm_k<<<dim3(1, 2, 8), 256, 0, stream>>>(gm);

  mdn_fin<<<256, 128, 0, stream>>>(ws_mdn, 8, (const float*)d_in[28], out);
}